// Round 1
// baseline (331461.694 us; speedup 1.0000x reference)
//
#include <hip/hip_runtime.h>
#include <math.h>

// ---------------------------------------------------------------------------
// DefaultHumanoidGRUCritic on MI355X
//
// Structure:
//   k0  concat_kernel    : build obs[T,341] from the 13 input arrays
//   k1  transpose_kernel : w_ih0[1536,341] -> wT[341,1536] (for coalesced GEMM)
//   k2  ig0_kernel       : IG0[T,1536] = obs @ w_ih0^T + b_ih0   (parallel over T)
//   k3  seq_kernel       : the recurrence. 128 workgroups:
//                            wgs [0,64)  : layer-0 GRU, publish h0_all[t] + progA
//                            wgs [64,128): layer-1 GRU, consume h0_all[t], publish h1_all[t]
//                          weights held in REGISTERS (96 floats/thread max);
//                          cross-wg sync via per-wg progress flags (agent-scope
//                          acquire/release), no grid barrier. Stage A never waits
//                          on stage B.
//   k4  mlp_kernel       : batched projector head over h1_all -> d_out[0..T)
// Final hidden states written by k3 leaders into d_out[T .. T+1024).
// ---------------------------------------------------------------------------

#define T_STEPS 16384
#define IN_DIM 341
#define HID 512
#define G3 1536
#define NA 64
#define NB 64
#define TTILE 16

__device__ __forceinline__ float dot4(float4 a, float4 b) {
  return fmaf(a.x, b.x, fmaf(a.y, b.y, fmaf(a.z, b.z, a.w * b.w)));
}

__device__ __forceinline__ float sigmoidf_(float x) {
  return 1.0f / (1.0f + expf(-x));
}

// ---- k0: concat observations ----------------------------------------------
__global__ __launch_bounds__(384) void concat_kernel(
    const float* __restrict__ p0, const float* __restrict__ p1,
    const float* __restrict__ p2, const float* __restrict__ p3,
    const float* __restrict__ p4, const float* __restrict__ p5,
    const float* __restrict__ p6, const float* __restrict__ p7,
    const float* __restrict__ p8, const float* __restrict__ p9,
    const float* __restrict__ p10, const float* __restrict__ p11,
    const float* __restrict__ p12, float* __restrict__ obs) {
  int t = blockIdx.x;
  int k = threadIdx.x;
  if (k >= IN_DIM) return;
  float v;
  if (k < 21)       v = p0[t*21 + k];
  else if (k < 42)  v = p1[t*21 + (k-21)];
  else if (k < 202) v = p2[t*160 + (k-42)];
  else if (k < 298) v = p3[t*96 + (k-202)];
  else if (k < 301) v = p4[t*3 + (k-298)];
  else if (k < 304) v = p5[t*3 + (k-301)];
  else if (k < 325) v = p6[t*21 + (k-304)];
  else if (k < 328) v = p7[t*3 + (k-325)];
  else if (k < 332) v = p8[t*4 + (k-328)];
  else if (k < 335) v = p9[t*3 + (k-332)];
  else if (k < 338) v = p10[t*3 + (k-335)];
  else if (k < 340) v = p11[t*2 + (k-338)];
  else              v = p12[t];
  obs[(size_t)t*IN_DIM + k] = v;
}

// ---- k1: transpose w_ih0 ---------------------------------------------------
__global__ __launch_bounds__(256) void transpose_kernel(const float* __restrict__ w,
                                                        float* __restrict__ wT) {
  __shared__ float tile[32][33];
  int tx = threadIdx.x;  // 32
  int ty = threadIdx.y;  // 8
  int k = blockIdx.x*32 + tx;
#pragma unroll
  for (int jj = 0; jj < 4; jj++) {
    int r = blockIdx.y*32 + ty*4 + jj;
    tile[ty*4+jj][tx] = (k < IN_DIM) ? w[(size_t)r*IN_DIM + k] : 0.f;
  }
  __syncthreads();
#pragma unroll
  for (int jj = 0; jj < 4; jj++) {
    int kk = blockIdx.x*32 + ty*4 + jj;
    if (kk < IN_DIM) wT[(size_t)kk*G3 + blockIdx.y*32 + tx] = tile[tx][ty*4+jj];
  }
}

// ---- k2: IG0 = obs @ w_ih0^T + b_ih0 --------------------------------------
// block: 256 threads = 256 output columns; grid.x = 6 (1536/256), grid.y = T/16.
// obs reads are wave-uniform (scalar loads); wT reads are coalesced.
__global__ __launch_bounds__(256) void ig0_kernel(const float* __restrict__ wT,
                                                  const float* __restrict__ obs,
                                                  const float* __restrict__ b_ih0,
                                                  float* __restrict__ ig0) {
  int o = blockIdx.x*256 + threadIdx.x;
  int t0 = blockIdx.y * TTILE;
  float acc[TTILE];
  float b = b_ih0[o];
#pragma unroll
  for (int tt = 0; tt < TTILE; tt++) acc[tt] = b;
  for (int k = 0; k < IN_DIM; k++) {
    float wv = wT[(size_t)k*G3 + o];
#pragma unroll
    for (int tt = 0; tt < TTILE; tt++)
      acc[tt] = fmaf(obs[(size_t)(t0+tt)*IN_DIM + k], wv, acc[tt]);
  }
#pragma unroll
  for (int tt = 0; tt < TTILE; tt++)
    ig0[(size_t)(t0+tt)*G3 + o] = acc[tt];
}

// ---- k3: sequential GRU scan ----------------------------------------------
__device__ __forceinline__ void wait_all(unsigned* prog, unsigned needed, int skip) {
  int l = threadIdx.x & 63;
  while (true) {
    unsigned v = __hip_atomic_load(&prog[l], __ATOMIC_ACQUIRE, __HIP_MEMORY_SCOPE_AGENT);
    bool ok = (l == skip) || (v >= needed);
    if (__ballot(ok) == ~0ull) break;
    __builtin_amdgcn_s_sleep(1);
  }
}

__device__ __forceinline__ void wait_ab(unsigned* progA, unsigned needA,
                                        unsigned* progB, unsigned needB, int skipB) {
  int l = threadIdx.x & 63;
  while (true) {
    unsigned va = __hip_atomic_load(&progA[l], __ATOMIC_ACQUIRE, __HIP_MEMORY_SCOPE_AGENT);
    unsigned vb = __hip_atomic_load(&progB[l], __ATOMIC_ACQUIRE, __HIP_MEMORY_SCOPE_AGENT);
    bool okA = (va >= needA);
    bool okB = (l == skipB) || (vb >= needB);
    if ((__ballot(okA) == ~0ull) && (__ballot(okB) == ~0ull)) break;
    __builtin_amdgcn_s_sleep(1);
  }
}

__global__ __launch_bounds__(256) void seq_kernel(
    const float* __restrict__ ig0, const float* __restrict__ w_hh0,
    const float* __restrict__ b_n0, const float* __restrict__ w_ih1,
    const float* __restrict__ w_hh1, const float* __restrict__ b_ih1,
    const float* __restrict__ b_n1, const float* __restrict__ hid,
    float* __restrict__ h0_all, float* __restrict__ h1_all,
    unsigned* progA, unsigned* progB, float* __restrict__ d_out) {
  const int tid = threadIdx.x;
  const int lane = tid & 63;
  const int wave = tid >> 6;
  const int el = wave*2 + (lane >> 5);  // 0..7 (element within wg)
  const int j = lane & 31;              // 0..31 (k-slice within element)
  const int kbase = j*16;
  const bool leader = (j == 0);

  if ((int)blockIdx.x < NA) {
    // ---------------- stage A: layer-0 GRU ----------------
    const int wg = blockIdx.x;
    const int eg = wg*8 + el;  // global h element 0..511
    float4 wr[4], wz[4], wn[4];
    {
      const float4* pr_ = (const float4*)(w_hh0 + (size_t)eg*HID + kbase);
      const float4* pz_ = (const float4*)(w_hh0 + (size_t)(512+eg)*HID + kbase);
      const float4* pn_ = (const float4*)(w_hh0 + (size_t)(1024+eg)*HID + kbase);
#pragma unroll
      for (int i = 0; i < 4; i++) { wr[i]=pr_[i]; wz[i]=pz_[i]; wn[i]=pn_[i]; }
    }
    const float bn = b_n0[eg];
    float hprev = hid[eg];
    for (int t = 0; t < T_STEPS; t++) {
      float igr=0.f, igz=0.f, ign=0.f;
      if (leader) {  // issue early; ready long before use
        const float* ig = ig0 + (size_t)t*G3;
        igr = ig[eg]; igz = ig[512+eg]; ign = ig[1024+eg];
      }
      if (t > 0) wait_all(progA, (unsigned)t, wg);
      const float* hsrc = t ? (h0_all + (size_t)(t-1)*HID) : hid;
      const float4* hp = (const float4*)(hsrc + kbase);
      float pr=0.f, pz=0.f, pn=0.f;
#pragma unroll
      for (int i = 0; i < 4; i++) {
        float4 hv = hp[i];
        pr += dot4(wr[i],hv); pz += dot4(wz[i],hv); pn += dot4(wn[i],hv);
      }
#pragma unroll
      for (int s = 16; s > 0; s >>= 1) {
        pr += __shfl_down(pr,s,32);
        pz += __shfl_down(pz,s,32);
        pn += __shfl_down(pn,s,32);
      }
      if (leader) {
        float r = sigmoidf_(igr + pr);
        float z = sigmoidf_(igz + pz);
        float n = tanhf(ign + r*(pn + bn));
        float hnew = n + z*(hprev - n);
        h0_all[(size_t)t*HID + eg] = hnew;
        hprev = hnew;
        if (t == T_STEPS-1) d_out[T_STEPS + eg] = hnew;
      }
      __threadfence();
      __syncthreads();
      if (tid == 0)
        __hip_atomic_store(&progA[wg], (unsigned)(t+1), __ATOMIC_RELEASE,
                           __HIP_MEMORY_SCOPE_AGENT);
    }
  } else {
    // ---------------- stage B: layer-1 GRU ----------------
    const int wg = blockIdx.x - NA;
    const int eg = wg*8 + el;
    float4 ur[4], uz[4], un[4];  // w_ih1 rows (input = h0_t)
    float4 vr[4], vz[4], vn[4];  // w_hh1 rows (input = h1_{t-1})
    {
      const float4* a0 = (const float4*)(w_ih1 + (size_t)eg*HID + kbase);
      const float4* a1 = (const float4*)(w_ih1 + (size_t)(512+eg)*HID + kbase);
      const float4* a2 = (const float4*)(w_ih1 + (size_t)(1024+eg)*HID + kbase);
      const float4* b0 = (const float4*)(w_hh1 + (size_t)eg*HID + kbase);
      const float4* b1 = (const float4*)(w_hh1 + (size_t)(512+eg)*HID + kbase);
      const float4* b2 = (const float4*)(w_hh1 + (size_t)(1024+eg)*HID + kbase);
#pragma unroll
      for (int i = 0; i < 4; i++) {
        ur[i]=a0[i]; uz[i]=a1[i]; un[i]=a2[i];
        vr[i]=b0[i]; vz[i]=b1[i]; vn[i]=b2[i];
      }
    }
    const float cr = b_ih1[eg], cz = b_ih1[512+eg], cn = b_ih1[1024+eg];
    const float bnn = b_n1[eg];
    float hprev = hid[HID + eg];
    for (int t = 0; t < T_STEPS; t++) {
      wait_ab(progA, (unsigned)(t+1), progB, (unsigned)t, wg);
      const float* h0src = h0_all + (size_t)t*HID;
      const float* h1src = t ? (h1_all + (size_t)(t-1)*HID) : (hid + HID);
      const float4* hp0 = (const float4*)(h0src + kbase);
      const float4* hp1 = (const float4*)(h1src + kbase);
      float pr=0.f, pz=0.f, pin=0.f, phn=0.f;
#pragma unroll
      for (int i = 0; i < 4; i++) {
        float4 h0v = hp0[i];
        float4 h1v = hp1[i];
        pr  += dot4(ur[i],h0v) + dot4(vr[i],h1v);
        pz  += dot4(uz[i],h0v) + dot4(vz[i],h1v);
        pin += dot4(un[i],h0v);
        phn += dot4(vn[i],h1v);
      }
#pragma unroll
      for (int s = 16; s > 0; s >>= 1) {
        pr  += __shfl_down(pr,s,32);
        pz  += __shfl_down(pz,s,32);
        pin += __shfl_down(pin,s,32);
        phn += __shfl_down(phn,s,32);
      }
      if (leader) {
        float r = sigmoidf_(pr + cr);
        float z = sigmoidf_(pz + cz);
        float n = tanhf(pin + cn + r*(phn + bnn));
        float hnew = n + z*(hprev - n);
        h1_all[(size_t)t*HID + eg] = hnew;
        hprev = hnew;
        if (t == T_STEPS-1) d_out[T_STEPS + HID + eg] = hnew;
      }
      __threadfence();
      __syncthreads();
      if (tid == 0)
        __hip_atomic_store(&progB[wg], (unsigned)(t+1), __ATOMIC_RELEASE,
                           __HIP_MEMORY_SCOPE_AGENT);
    }
  }
}

// ---- k4: batched MLP head --------------------------------------------------
// one wave per block, 8 timesteps per block.
__global__ __launch_bounds__(64) void mlp_kernel(
    const float* __restrict__ h1_all, const float* __restrict__ mw0,
    const float* __restrict__ mb0, const float* __restrict__ mw1,
    const float* __restrict__ mb1, const float* __restrict__ mw2,
    const float* __restrict__ mb2, float* __restrict__ out) {
  const int l = threadIdx.x;
  const int t0 = blockIdx.x * 8;
  __shared__ float v0s[8][64];
  float acc[8];
#pragma unroll
  for (int tt = 0; tt < 8; tt++) acc[tt] = mb0[l];
  const float4* w = (const float4*)(mw0 + (size_t)l*512);
#pragma unroll 4
  for (int i = 0; i < 128; i++) {
    float4 a = w[i];
#pragma unroll
    for (int tt = 0; tt < 8; tt++) {
      float4 b = ((const float4*)(h1_all + (size_t)(t0+tt)*512))[i];
      acc[tt] = fmaf(a.x,b.x, fmaf(a.y,b.y, fmaf(a.z,b.z, fmaf(a.w,b.w, acc[tt]))));
    }
  }
#pragma unroll
  for (int tt = 0; tt < 8; tt++) v0s[tt][l] = fmaxf(acc[tt], 0.f);
  __syncthreads();
  float acc1[8];
#pragma unroll
  for (int tt = 0; tt < 8; tt++) acc1[tt] = mb1[l];
  const float* w1 = mw1 + (size_t)l*64;
  for (int jj = 0; jj < 64; jj++) {
    float wv = w1[jj];
#pragma unroll
    for (int tt = 0; tt < 8; tt++) acc1[tt] = fmaf(wv, v0s[tt][jj], acc1[tt]);
  }
  float w2 = mw2[l];
  float bb = mb2[0];
#pragma unroll
  for (int tt = 0; tt < 8; tt++) {
    float y = w2 * fmaxf(acc1[tt], 0.f);
#pragma unroll
    for (int s = 32; s > 0; s >>= 1) y += __shfl_down(y, s, 64);
    if (l == 0) out[t0+tt] = y + bb;
  }
}

// ---------------------------------------------------------------------------
extern "C" void kernel_launch(void* const* d_in, const int* in_sizes, int n_in,
                              void* d_out, int out_size, void* d_ws, size_t ws_size,
                              hipStream_t stream) {
  const float* p0  = (const float*)d_in[0];
  const float* p1  = (const float*)d_in[1];
  const float* p2  = (const float*)d_in[2];
  const float* p3  = (const float*)d_in[3];
  const float* p4  = (const float*)d_in[4];
  const float* p5  = (const float*)d_in[5];
  const float* p6  = (const float*)d_in[6];
  const float* p7  = (const float*)d_in[7];
  const float* p8  = (const float*)d_in[8];
  const float* p9  = (const float*)d_in[9];
  const float* p10 = (const float*)d_in[10];
  const float* p11 = (const float*)d_in[11];
  const float* p12 = (const float*)d_in[12];
  const float* hid   = (const float*)d_in[13];
  const float* w_ih0 = (const float*)d_in[14];
  const float* w_hh0 = (const float*)d_in[15];
  const float* b_ih0 = (const float*)d_in[16];
  const float* b_n0  = (const float*)d_in[17];
  const float* w_ih1 = (const float*)d_in[18];
  const float* w_hh1 = (const float*)d_in[19];
  const float* b_ih1 = (const float*)d_in[20];
  const float* b_n1  = (const float*)d_in[21];
  const float* mw0 = (const float*)d_in[22];
  const float* mb0 = (const float*)d_in[23];
  const float* mw1 = (const float*)d_in[24];
  const float* mb1 = (const float*)d_in[25];
  const float* mw2 = (const float*)d_in[26];
  const float* mb2 = (const float*)d_in[27];
  float* out = (float*)d_out;

  char* base = (char*)d_ws;
  size_t off = 0;
  float* obs = (float*)(base + off); off += (size_t)T_STEPS*IN_DIM*4;
  float* wT  = (float*)(base + off); off += (size_t)IN_DIM*G3*4;
  float* ig0 = (float*)(base + off); off += (size_t)T_STEPS*G3*4;
  float* h0a = (float*)(base + off); off += (size_t)T_STEPS*HID*4;
  float* h1a = (float*)(base + off); off += (size_t)T_STEPS*HID*4;
  unsigned* progA = (unsigned*)(base + off); off += 256;
  unsigned* progB = (unsigned*)(base + off); off += 256;
  if (ws_size < off) return;  // workspace too small: fail cleanly

  hipMemsetAsync(progA, 0, 512, stream);
  concat_kernel<<<T_STEPS, 384, 0, stream>>>(p0,p1,p2,p3,p4,p5,p6,p7,p8,p9,p10,p11,p12, obs);
  transpose_kernel<<<dim3(11,48), dim3(32,8), 0, stream>>>(w_ih0, wT);
  ig0_kernel<<<dim3(6, T_STEPS/TTILE), 256, 0, stream>>>(wT, obs, b_ih0, ig0);
  seq_kernel<<<NA+NB, 256, 0, stream>>>(ig0, w_hh0, b_n0, w_ih1, w_hh1, b_ih1, b_n1,
                                        hid, h0a, h1a, progA, progB, out);
  mlp_kernel<<<T_STEPS/8, 64, 0, stream>>>(h1a, mw0, mb0, mw1, mb1, mw2, mb2, out);
}

// Round 2
// 109573.413 us; speedup vs baseline: 3.0250x; 3.0250x over previous
//
#include <hip/hip_runtime.h>
#include <math.h>

// ---------------------------------------------------------------------------
// DefaultHumanoidGRUCritic on MI355X — round 2
//
// Round-1 failure mode (measured): acquire/release agent atomics + threadfence
// per step = L2 writeback/invalidate storms -> 22.5us/step, 880MB HBM refetch,
// VALUBusy 0.8%. Fix: ALL cross-wg communication is 64-bit RELAXED agent-scope
// atomics packing (tag=step+1, fp32 value). Self-timed data => no fences, no
// syncthreads, no cache maintenance. Weights/ig0 stay cached.
//
//   k0 concat   : obs[T,341]              (obs aliased into h1a region)
//   k1 transpose: w_ih0 -> wT[341,1536]   (wT  aliased into h1a region)
//   k2 ig0      : IG0[T,1536] = obs @ w_ih0^T + b_ih0  (parallel over T)
//   k3 seq      : 128 wgs x 256. wg<64: layer-0 GRU (one 32-lane group per h
//                 element, weights in regs, publish tagged h0 into 4096-slot
//                 ring). wg>=64: layer-1 GRU (consume tagged h0, publish
//                 tagged h1 into 4-slot ring + plain h1a for the MLP).
//                 A throttles on coarse B-progress flags every 2048 steps.
//   k4 mlp      : batched projector head over h1a -> d_out[0..T)
// Final hidden states -> d_out[T .. T+1024).
// ---------------------------------------------------------------------------

#define T_STEPS 16384
#define IN_DIM 341
#define HID 512
#define G3 1536
#define TTILE 16
#define RING0 4096   // h0 ring slots (power of 2)
#define RING1 4      // h1 ring slots

__device__ __forceinline__ float dot4(float4 a, float4 b) {
  return fmaf(a.x, b.x, fmaf(a.y, b.y, fmaf(a.z, b.z, a.w * b.w)));
}
__device__ __forceinline__ float fast_sigmoid(float x) {
  return __builtin_amdgcn_rcpf(1.0f + __expf(-x));
}
__device__ __forceinline__ float fast_tanh(float x) {
  // tanh(x) = 1 - 2/(exp(2x)+1); saturates correctly at +-inf
  return fmaf(-2.0f, __builtin_amdgcn_rcpf(1.0f + __expf(2.0f * x)), 1.0f);
}
__device__ __forceinline__ unsigned long long ld_rlx(const unsigned long long* p) {
  return __hip_atomic_load(p, __ATOMIC_RELAXED, __HIP_MEMORY_SCOPE_AGENT);
}
__device__ __forceinline__ void st_rlx(unsigned long long* p, unsigned long long v) {
  __hip_atomic_store(p, v, __ATOMIC_RELAXED, __HIP_MEMORY_SCOPE_AGENT);
}

// ---- k0: concat observations ----------------------------------------------
__global__ __launch_bounds__(384) void concat_kernel(
    const float* __restrict__ p0, const float* __restrict__ p1,
    const float* __restrict__ p2, const float* __restrict__ p3,
    const float* __restrict__ p4, const float* __restrict__ p5,
    const float* __restrict__ p6, const float* __restrict__ p7,
    const float* __restrict__ p8, const float* __restrict__ p9,
    const float* __restrict__ p10, const float* __restrict__ p11,
    const float* __restrict__ p12, float* __restrict__ obs) {
  int t = blockIdx.x;
  int k = threadIdx.x;
  if (k >= IN_DIM) return;
  float v;
  if (k < 21)       v = p0[t*21 + k];
  else if (k < 42)  v = p1[t*21 + (k-21)];
  else if (k < 202) v = p2[t*160 + (k-42)];
  else if (k < 298) v = p3[t*96 + (k-202)];
  else if (k < 301) v = p4[t*3 + (k-298)];
  else if (k < 304) v = p5[t*3 + (k-301)];
  else if (k < 325) v = p6[t*21 + (k-304)];
  else if (k < 328) v = p7[t*3 + (k-325)];
  else if (k < 332) v = p8[t*4 + (k-328)];
  else if (k < 335) v = p9[t*3 + (k-332)];
  else if (k < 338) v = p10[t*3 + (k-335)];
  else if (k < 340) v = p11[t*2 + (k-338)];
  else              v = p12[t];
  obs[(size_t)t*IN_DIM + k] = v;
}

// ---- k1: transpose w_ih0 ---------------------------------------------------
__global__ __launch_bounds__(256) void transpose_kernel(const float* __restrict__ w,
                                                        float* __restrict__ wT) {
  __shared__ float tile[32][33];
  int tx = threadIdx.x;  // 32
  int ty = threadIdx.y;  // 8
  int k = blockIdx.x*32 + tx;
#pragma unroll
  for (int jj = 0; jj < 4; jj++) {
    int r = blockIdx.y*32 + ty*4 + jj;
    tile[ty*4+jj][tx] = (k < IN_DIM) ? w[(size_t)r*IN_DIM + k] : 0.f;
  }
  __syncthreads();
#pragma unroll
  for (int jj = 0; jj < 4; jj++) {
    int kk = blockIdx.x*32 + ty*4 + jj;
    if (kk < IN_DIM) wT[(size_t)kk*G3 + blockIdx.y*32 + tx] = tile[tx][ty*4+jj];
  }
}

// ---- k2: IG0 = obs @ w_ih0^T + b_ih0 --------------------------------------
__global__ __launch_bounds__(256) void ig0_kernel(const float* __restrict__ wT,
                                                  const float* __restrict__ obs,
                                                  const float* __restrict__ b_ih0,
                                                  float* __restrict__ ig0) {
  int o = blockIdx.x*256 + threadIdx.x;
  int t0 = blockIdx.y * TTILE;
  float acc[TTILE];
  float b = b_ih0[o];
#pragma unroll
  for (int tt = 0; tt < TTILE; tt++) acc[tt] = b;
  for (int k = 0; k < IN_DIM; k++) {
    float wv = wT[(size_t)k*G3 + o];
#pragma unroll
    for (int tt = 0; tt < TTILE; tt++)
      acc[tt] = fmaf(obs[(size_t)(t0+tt)*IN_DIM + k], wv, acc[tt]);
  }
#pragma unroll
  for (int tt = 0; tt < TTILE; tt++)
    ig0[(size_t)(t0+tt)*G3 + o] = acc[tt];
}

// ---- k3: sequential GRU scan (fence-free tagged atomics) -------------------
__global__ __launch_bounds__(256) void seq_kernel(
    const float* __restrict__ ig0, const float* __restrict__ w_hh0,
    const float* __restrict__ b_n0, const float* __restrict__ w_ih1,
    const float* __restrict__ w_hh1, const float* __restrict__ b_ih1,
    const float* __restrict__ b_n1, const float* __restrict__ hid,
    unsigned long long* ring0, unsigned long long* ring1,
    unsigned* progB, float* __restrict__ h1a, float* __restrict__ d_out) {
  const int tid = threadIdx.x;
  const int lane = tid & 63;
  const int wave = tid >> 6;
  const int el = wave*2 + (lane >> 5);   // 0..7: element group within wg
  const int j = lane & 31;               // 0..31: k-slice within element
  const int kbase = j * 16;
  const bool leader = (j == 0);
  const unsigned long long gmask =
      (lane < 32) ? 0xFFFFFFFFull : 0xFFFFFFFF00000000ull;

  if ((int)blockIdx.x < 64) {
    // ---------------- stage A: layer-0 GRU ----------------
    const int eg = (int)blockIdx.x * 8 + el;   // h0 element 0..511
    float4 wr[4], wz[4], wn[4];
    {
      const float4* pr_ = (const float4*)(w_hh0 + (size_t)eg*HID + kbase);
      const float4* pz_ = (const float4*)(w_hh0 + (size_t)(512+eg)*HID + kbase);
      const float4* pn_ = (const float4*)(w_hh0 + (size_t)(1024+eg)*HID + kbase);
#pragma unroll
      for (int i = 0; i < 4; i++) { wr[i]=pr_[i]; wz[i]=pz_[i]; wn[i]=pn_[i]; }
    }
    const float bn = b_n0[eg];
    float hprev = hid[eg];
    for (int t = 0; t < T_STEPS; t++) {
      float igr=0.f, igz=0.f, ign=0.f;
      if (leader) {  // cached loads, issued before the poll
        const float* ig = ig0 + (size_t)t*G3;
        igr = ig[eg]; igz = ig[512+eg]; ign = ig[1024+eg];
      }
      // ring-overwrite throttle: next 2048 steps destroy h0[t-RING0 ..];
      // require all B groups past them. progB staleness <= 64 steps.
      if ((t & 2047) == 0 && t >= RING0) {
        const int need = t + 2048 - RING0;
        while (true) {
          unsigned mn = 0xFFFFFFFFu;
#pragma unroll
          for (int i = 0; i < 16; i++) {
            unsigned v = __hip_atomic_load(&progB[j*16+i], __ATOMIC_RELAXED,
                                           __HIP_MEMORY_SCOPE_AGENT);
            mn = v < mn ? v : mn;
          }
#pragma unroll
          for (int s = 16; s > 0; s >>= 1) {
            unsigned o = __shfl_xor(mn, s, 32);
            mn = o < mn ? o : mn;
          }
          if ((int)mn >= need) break;
          __builtin_amdgcn_s_sleep(16);
        }
      }
      float hv[16];
      if (t == 0) {
        const float* hp = hid + kbase;
#pragma unroll
        for (int i = 0; i < 16; i++) hv[i] = hp[i];
      } else {
        const unsigned long long* src =
            ring0 + (size_t)((t-1) & (RING0-1))*HID + kbase;
        const unsigned want = (unsigned)t;
        while (true) {  // phase 1: cheap spin on one word per lane
          unsigned long long a = ld_rlx(&src[0]);
          bool ok = ((unsigned)(a >> 32) == want);
          if ((__ballot(ok) & gmask) == gmask) break;
          __builtin_amdgcn_s_sleep(1);
        }
        unsigned long long wb[16];
        while (true) {  // phase 2: batch load + verify all tags
#pragma unroll
          for (int i = 0; i < 16; i++) wb[i] = ld_rlx(&src[i]);
          bool ok = true;
#pragma unroll
          for (int i = 0; i < 16; i++) ok &= ((unsigned)(wb[i] >> 32) == want);
          if ((__ballot(ok) & gmask) == gmask) break;
        }
#pragma unroll
        for (int i = 0; i < 16; i++) hv[i] = __uint_as_float((unsigned)wb[i]);
      }
      float pr=0.f, pz=0.f, pn=0.f;
#pragma unroll
      for (int i = 0; i < 4; i++) {
        float4 h4 = make_float4(hv[4*i], hv[4*i+1], hv[4*i+2], hv[4*i+3]);
        pr += dot4(wr[i],h4); pz += dot4(wz[i],h4); pn += dot4(wn[i],h4);
      }
#pragma unroll
      for (int s = 16; s > 0; s >>= 1) {
        pr += __shfl_down(pr,s,32);
        pz += __shfl_down(pz,s,32);
        pn += __shfl_down(pn,s,32);
      }
      if (leader) {
        float r = fast_sigmoid(igr + pr);
        float z = fast_sigmoid(igz + pz);
        float n = fast_tanh(ign + r*(pn + bn));
        float hnew = n + z*(hprev - n);
        hprev = hnew;
        unsigned long long pk =
            ((unsigned long long)(unsigned)(t+1) << 32) |
            (unsigned long long)__float_as_uint(hnew);
        st_rlx(&ring0[(size_t)(t & (RING0-1))*HID + eg], pk);
        if (t == T_STEPS-1) d_out[T_STEPS + eg] = hnew;
      }
    }
  } else {
    // ---------------- stage B: layer-1 GRU ----------------
    const int eg = ((int)blockIdx.x - 64) * 8 + el;  // h1 element 0..511
    float4 ur[4], uz[4], un[4], vr[4], vz[4], vn[4];
    {
      const float4* a0 = (const float4*)(w_ih1 + (size_t)eg*HID + kbase);
      const float4* a1 = (const float4*)(w_ih1 + (size_t)(512+eg)*HID + kbase);
      const float4* a2 = (const float4*)(w_ih1 + (size_t)(1024+eg)*HID + kbase);
      const float4* b0 = (const float4*)(w_hh1 + (size_t)eg*HID + kbase);
      const float4* b1 = (const float4*)(w_hh1 + (size_t)(512+eg)*HID + kbase);
      const float4* b2 = (const float4*)(w_hh1 + (size_t)(1024+eg)*HID + kbase);
#pragma unroll
      for (int i = 0; i < 4; i++) {
        ur[i]=a0[i]; uz[i]=a1[i]; un[i]=a2[i];
        vr[i]=b0[i]; vz[i]=b1[i]; vn[i]=b2[i];
      }
    }
    const float cr = b_ih1[eg], cz = b_ih1[512+eg], cn = b_ih1[1024+eg];
    const float bnn = b_n1[eg];
    float hprev = hid[HID + eg];
    for (int t = 0; t < T_STEPS; t++) {
      const unsigned long long* s0 =
          ring0 + (size_t)(t & (RING0-1))*HID + kbase;
      const unsigned long long* s1 =
          ring1 + (size_t)((t-1) & (RING1-1))*HID + kbase;
      const unsigned want0 = (unsigned)(t+1);
      const unsigned want1 = (unsigned)t;
      const bool need1 = (t > 0);
      while (true) {  // phase 1
        unsigned long long a = ld_rlx(&s0[0]);
        bool ok = ((unsigned)(a >> 32) == want0);
        if (need1) {
          unsigned long long b = ld_rlx(&s1[0]);
          ok &= ((unsigned)(b >> 32) == want1);
        }
        if ((__ballot(ok) & gmask) == gmask) break;
        __builtin_amdgcn_s_sleep(1);
      }
      unsigned long long wb0[16], wb1[16];
      while (true) {  // phase 2
        bool ok = true;
#pragma unroll
        for (int i = 0; i < 16; i++) wb0[i] = ld_rlx(&s0[i]);
#pragma unroll
        for (int i = 0; i < 16; i++) ok &= ((unsigned)(wb0[i] >> 32) == want0);
        if (need1) {
#pragma unroll
          for (int i = 0; i < 16; i++) wb1[i] = ld_rlx(&s1[i]);
#pragma unroll
          for (int i = 0; i < 16; i++) ok &= ((unsigned)(wb1[i] >> 32) == want1);
        }
        if ((__ballot(ok) & gmask) == gmask) break;
      }
      float h0v[16], h1v[16];
#pragma unroll
      for (int i = 0; i < 16; i++) h0v[i] = __uint_as_float((unsigned)wb0[i]);
      if (need1) {
#pragma unroll
        for (int i = 0; i < 16; i++) h1v[i] = __uint_as_float((unsigned)wb1[i]);
      } else {
        const float* hp = hid + HID + kbase;
#pragma unroll
        for (int i = 0; i < 16; i++) h1v[i] = hp[i];
      }
      float pr=0.f, pz=0.f, pin=0.f, phn=0.f;
#pragma unroll
      for (int i = 0; i < 4; i++) {
        float4 a = make_float4(h0v[4*i], h0v[4*i+1], h0v[4*i+2], h0v[4*i+3]);
        float4 b = make_float4(h1v[4*i], h1v[4*i+1], h1v[4*i+2], h1v[4*i+3]);
        pr  += dot4(ur[i],a) + dot4(vr[i],b);
        pz  += dot4(uz[i],a) + dot4(vz[i],b);
        pin += dot4(un[i],a);
        phn += dot4(vn[i],b);
      }
#pragma unroll
      for (int s = 16; s > 0; s >>= 1) {
        pr  += __shfl_down(pr,s,32);
        pz  += __shfl_down(pz,s,32);
        pin += __shfl_down(pin,s,32);
        phn += __shfl_down(phn,s,32);
      }
      if (leader) {
        float r = fast_sigmoid(pr + cr);
        float z = fast_sigmoid(pz + cz);
        float n = fast_tanh(pin + cn + r*(phn + bnn));
        float hnew = n + z*(hprev - n);
        hprev = hnew;
        unsigned long long pk =
            ((unsigned long long)(unsigned)(t+1) << 32) |
            (unsigned long long)__float_as_uint(hnew);
        st_rlx(&ring1[(size_t)(t & (RING1-1))*HID + eg], pk);
        h1a[(size_t)t*HID + eg] = hnew;  // plain cached store for the MLP
        if ((t & 63) == 63)
          __hip_atomic_store(&progB[eg], (unsigned)(t+1), __ATOMIC_RELAXED,
                             __HIP_MEMORY_SCOPE_AGENT);
        if (t == T_STEPS-1) d_out[T_STEPS + HID + eg] = hnew;
      }
    }
  }
}

// ---- k4: batched MLP head --------------------------------------------------
__global__ __launch_bounds__(64) void mlp_kernel(
    const float* __restrict__ h1_all, const float* __restrict__ mw0,
    const float* __restrict__ mb0, const float* __restrict__ mw1,
    const float* __restrict__ mb1, const float* __restrict__ mw2,
    const float* __restrict__ mb2, float* __restrict__ out) {
  const int l = threadIdx.x;
  const int t0 = blockIdx.x * 8;
  __shared__ float v0s[8][64];
  float acc[8];
#pragma unroll
  for (int tt = 0; tt < 8; tt++) acc[tt] = mb0[l];
  const float4* w = (const float4*)(mw0 + (size_t)l*512);
#pragma unroll 4
  for (int i = 0; i < 128; i++) {
    float4 a = w[i];
#pragma unroll
    for (int tt = 0; tt < 8; tt++) {
      float4 b = ((const float4*)(h1_all + (size_t)(t0+tt)*512))[i];
      acc[tt] = fmaf(a.x,b.x, fmaf(a.y,b.y, fmaf(a.z,b.z, fmaf(a.w,b.w, acc[tt]))));
    }
  }
#pragma unroll
  for (int tt = 0; tt < 8; tt++) v0s[tt][l] = fmaxf(acc[tt], 0.f);
  __syncthreads();
  float acc1[8];
#pragma unroll
  for (int tt = 0; tt < 8; tt++) acc1[tt] = mb1[l];
  const float* w1 = mw1 + (size_t)l*64;
  for (int jj = 0; jj < 64; jj++) {
    float wv = w1[jj];
#pragma unroll
    for (int tt = 0; tt < 8; tt++) acc1[tt] = fmaf(wv, v0s[tt][jj], acc1[tt]);
  }
  float w2 = mw2[l];
  float bb = mb2[0];
#pragma unroll
  for (int tt = 0; tt < 8; tt++) {
    float y = w2 * fmaxf(acc1[tt], 0.f);
#pragma unroll
    for (int s = 32; s > 0; s >>= 1) y += __shfl_down(y, s, 64);
    if (l == 0) out[t0+tt] = y + bb;
  }
}

// ---------------------------------------------------------------------------
extern "C" void kernel_launch(void* const* d_in, const int* in_sizes, int n_in,
                              void* d_out, int out_size, void* d_ws, size_t ws_size,
                              hipStream_t stream) {
  const float* p0  = (const float*)d_in[0];
  const float* p1  = (const float*)d_in[1];
  const float* p2  = (const float*)d_in[2];
  const float* p3  = (const float*)d_in[3];
  const float* p4  = (const float*)d_in[4];
  const float* p5  = (const float*)d_in[5];
  const float* p6  = (const float*)d_in[6];
  const float* p7  = (const float*)d_in[7];
  const float* p8  = (const float*)d_in[8];
  const float* p9  = (const float*)d_in[9];
  const float* p10 = (const float*)d_in[10];
  const float* p11 = (const float*)d_in[11];
  const float* p12 = (const float*)d_in[12];
  const float* hid   = (const float*)d_in[13];
  const float* w_ih0 = (const float*)d_in[14];
  const float* w_hh0 = (const float*)d_in[15];
  const float* b_ih0 = (const float*)d_in[16];
  const float* b_n0  = (const float*)d_in[17];
  const float* w_ih1 = (const float*)d_in[18];
  const float* w_hh1 = (const float*)d_in[19];
  const float* b_ih1 = (const float*)d_in[20];
  const float* b_n1  = (const float*)d_in[21];
  const float* mw0 = (const float*)d_in[22];
  const float* mb0 = (const float*)d_in[23];
  const float* mw1 = (const float*)d_in[24];
  const float* mb1 = (const float*)d_in[25];
  const float* mw2 = (const float*)d_in[26];
  const float* mb2 = (const float*)d_in[27];
  float* out = (float*)d_out;

  // workspace layout (151,013,376 B total; obs/wT alias the h1a region,
  // dead before seq_kernel writes h1a)
  char* base = (char*)d_ws;
  const size_t IG0_B   = (size_t)T_STEPS*G3*4;          // 100,663,296
  const size_t RING0_B = (size_t)RING0*HID*8;           //  16,777,216
  const size_t RING1_B = (size_t)RING1*HID*8;           //      16,384
  const size_t PROG_B  = 2048;
  const size_t H1A_B   = (size_t)T_STEPS*HID*4;         //  33,554,432
  float* ig0 = (float*)base;
  unsigned long long* ring0 = (unsigned long long*)(base + IG0_B);
  unsigned long long* ring1 = (unsigned long long*)(base + IG0_B + RING0_B);
  unsigned* progB = (unsigned*)(base + IG0_B + RING0_B + RING1_B);
  float* h1a = (float*)(base + IG0_B + RING0_B + RING1_B + PROG_B);
  float* obs = h1a;                                      // alias
  float* wT  = (float*)((char*)h1a + (size_t)T_STEPS*IN_DIM*4);  // alias
  if (ws_size < IG0_B + RING0_B + RING1_B + PROG_B + H1A_B) return;

  hipMemsetAsync(progB, 0, PROG_B, stream);
  concat_kernel<<<T_STEPS, 384, 0, stream>>>(p0,p1,p2,p3,p4,p5,p6,p7,p8,p9,p10,p11,p12, obs);
  transpose_kernel<<<dim3(11,48), dim3(32,8), 0, stream>>>(w_ih0, wT);
  ig0_kernel<<<dim3(6, T_STEPS/TTILE), 256, 0, stream>>>(wT, obs, b_ih0, ig0);
  seq_kernel<<<128, 256, 0, stream>>>(ig0, w_hh0, b_n0, w_ih1, w_hh1, b_ih1, b_n1,
                                      hid, ring0, ring1, progB, h1a, out);
  mlp_kernel<<<T_STEPS/8, 64, 0, stream>>>(h1a, mw0, mb0, mw1, mb1, mw2, mb2, out);
}

// Round 4
// 68192.645 us; speedup vs baseline: 4.8607x; 1.6068x over previous
//
#include <hip/hip_runtime.h>
#include <math.h>

// ---------------------------------------------------------------------------
// DefaultHumanoidGRUCritic on MI355X — round 4 (round 3 hardened)
//
// Round-2 lesson (measured): comm cost is LLC REQUEST THROUGHPUT, not latency.
// Round-3 structure: stage each published h-vector into LDS ONCE PER WG, all
// element-groups compute from LDS. Round 3 hung (container failed) with no
// counters; logic re-audit found no deadlock, but verify loops had NO backoff
// (32K lanes tight-spinning uncached loads on the MALL). This round: every
// verify loop gets a fast first probe + s_sleep(1) backoff. No other change.
//
//   k0 concat, k1 transpose, k2 ig0 (parallel over T; obs/wT alias h1a)
//   k_init    : seed ring0/ring1 slot 0 with tagged initial hidden state
//   k3 seq    : 128 WGs x 256. WG<64: layer-0 (8 elements each, weights in
//               regs, tagged ring0 of 2048 slots, coarse B-throttle).
//               WG>=64: layer-1 (consume ring0 + own 8-slot ring1, write
//               plain h1a for the MLP).
//   k4 mlp    : batched projector head over h1a -> d_out[0..T)
// Final hidden -> d_out[T .. T+1024).
// ---------------------------------------------------------------------------

#define T_STEPS 16384
#define IN_DIM 341
#define HID 512
#define G3 1536
#define TTILE 16
#define R0 2048     // ring0 slots (pow2)
#define R1 8        // ring1 slots (pow2)

__device__ __forceinline__ float dot4(float4 a, float4 b) {
  return fmaf(a.x, b.x, fmaf(a.y, b.y, fmaf(a.z, b.z, a.w * b.w)));
}
__device__ __forceinline__ float fast_sigmoid(float x) {
  return __builtin_amdgcn_rcpf(1.0f + __expf(-x));
}
__device__ __forceinline__ float fast_tanh(float x) {
  return fmaf(-2.0f, __builtin_amdgcn_rcpf(1.0f + __expf(2.0f * x)), 1.0f);
}
__device__ __forceinline__ unsigned long long ld_rlx64(const unsigned long long* p) {
  return __hip_atomic_load(p, __ATOMIC_RELAXED, __HIP_MEMORY_SCOPE_AGENT);
}
__device__ __forceinline__ void st_rlx64(unsigned long long* p, unsigned long long v) {
  __hip_atomic_store(p, v, __ATOMIC_RELAXED, __HIP_MEMORY_SCOPE_AGENT);
}
__device__ __forceinline__ unsigned ld_rlx32(const unsigned* p) {
  return __hip_atomic_load(p, __ATOMIC_RELAXED, __HIP_MEMORY_SCOPE_AGENT);
}
__device__ __forceinline__ void st_rlx32(unsigned* p, unsigned v) {
  __hip_atomic_store(p, v, __ATOMIC_RELAXED, __HIP_MEMORY_SCOPE_AGENT);
}
__device__ __forceinline__ unsigned long long pack_tv(unsigned tag, float v) {
  return ((unsigned long long)tag << 32) | (unsigned long long)__float_as_uint(v);
}
// tagged verify load with backoff: fast path = single load when data present
__device__ __forceinline__ float verify_ld(const unsigned long long* p, unsigned want) {
  unsigned long long w = ld_rlx64(p);
  while ((unsigned)(w >> 32) != want) {
    __builtin_amdgcn_s_sleep(1);
    w = ld_rlx64(p);
  }
  return __uint_as_float((unsigned)w);
}

// ---- k0: concat observations ----------------------------------------------
__global__ __launch_bounds__(384) void concat_kernel(
    const float* __restrict__ p0, const float* __restrict__ p1,
    const float* __restrict__ p2, const float* __restrict__ p3,
    const float* __restrict__ p4, const float* __restrict__ p5,
    const float* __restrict__ p6, const float* __restrict__ p7,
    const float* __restrict__ p8, const float* __restrict__ p9,
    const float* __restrict__ p10, const float* __restrict__ p11,
    const float* __restrict__ p12, float* __restrict__ obs) {
  int t = blockIdx.x;
  int k = threadIdx.x;
  if (k >= IN_DIM) return;
  float v;
  if (k < 21)       v = p0[t*21 + k];
  else if (k < 42)  v = p1[t*21 + (k-21)];
  else if (k < 202) v = p2[t*160 + (k-42)];
  else if (k < 298) v = p3[t*96 + (k-202)];
  else if (k < 301) v = p4[t*3 + (k-298)];
  else if (k < 304) v = p5[t*3 + (k-301)];
  else if (k < 325) v = p6[t*21 + (k-304)];
  else if (k < 328) v = p7[t*3 + (k-325)];
  else if (k < 332) v = p8[t*4 + (k-328)];
  else if (k < 335) v = p9[t*3 + (k-332)];
  else if (k < 338) v = p10[t*3 + (k-335)];
  else if (k < 340) v = p11[t*2 + (k-338)];
  else              v = p12[t];
  obs[(size_t)t*IN_DIM + k] = v;
}

// ---- k1: transpose w_ih0 ---------------------------------------------------
__global__ __launch_bounds__(256) void transpose_kernel(const float* __restrict__ w,
                                                        float* __restrict__ wT) {
  __shared__ float tile[32][33];
  int tx = threadIdx.x;  // 32
  int ty = threadIdx.y;  // 8
  int k = blockIdx.x*32 + tx;
#pragma unroll
  for (int jj = 0; jj < 4; jj++) {
    int r = blockIdx.y*32 + ty*4 + jj;
    tile[ty*4+jj][tx] = (k < IN_DIM) ? w[(size_t)r*IN_DIM + k] : 0.f;
  }
  __syncthreads();
#pragma unroll
  for (int jj = 0; jj < 4; jj++) {
    int kk = blockIdx.x*32 + ty*4 + jj;
    if (kk < IN_DIM) wT[(size_t)kk*G3 + blockIdx.y*32 + tx] = tile[tx][ty*4+jj];
  }
}

// ---- k2: IG0 = obs @ w_ih0^T + b_ih0 --------------------------------------
__global__ __launch_bounds__(256) void ig0_kernel(const float* __restrict__ wT,
                                                  const float* __restrict__ obs,
                                                  const float* __restrict__ b_ih0,
                                                  float* __restrict__ ig0) {
  int o = blockIdx.x*256 + threadIdx.x;
  int t0 = blockIdx.y * TTILE;
  float acc[TTILE];
  float b = b_ih0[o];
#pragma unroll
  for (int tt = 0; tt < TTILE; tt++) acc[tt] = b;
  for (int k = 0; k < IN_DIM; k++) {
    float wv = wT[(size_t)k*G3 + o];
#pragma unroll
    for (int tt = 0; tt < TTILE; tt++)
      acc[tt] = fmaf(obs[(size_t)(t0+tt)*IN_DIM + k], wv, acc[tt]);
  }
#pragma unroll
  for (int tt = 0; tt < TTILE; tt++)
    ig0[(size_t)(t0+tt)*G3 + o] = acc[tt];
}

// ---- k_init: seed ring slot 0 with tagged initial hidden -------------------
__global__ __launch_bounds__(512) void init_kernel(const float* __restrict__ hid,
                                                   unsigned long long* ring0,
                                                   unsigned long long* ring1) {
  int e = threadIdx.x;
  st_rlx64(&ring0[e], pack_tv(0u, hid[e]));
  st_rlx64(&ring1[e], pack_tv(0u, hid[HID + e]));
}

// ---- k3: sequential GRU scan ----------------------------------------------
// 128 WGs x 256 threads. Each WG owns 8 h-elements (one 32-lane group each).
// Published vectors staged ONCE per WG into LDS via tagged 8B verify loads.
__global__ __launch_bounds__(256) void seq_kernel(
    const float* __restrict__ ig0, const float* __restrict__ w_hh0,
    const float* __restrict__ b_n0, const float* __restrict__ w_ih1,
    const float* __restrict__ w_hh1, const float* __restrict__ b_ih1,
    const float* __restrict__ b_n1, const float* __restrict__ hid,
    unsigned long long* ring0, unsigned long long* ring1,
    unsigned* cntA, unsigned* cntB,
    float* __restrict__ h1a, float* __restrict__ d_out) {
  __shared__ float hbuf0[HID];
  __shared__ float hbuf1[HID];
  const int tid = threadIdx.x;
  const int g = tid >> 5;          // 0..7: element group
  const int j = tid & 31;          // k-slice lane within group
  const int kbase = j * 16;
  const bool leader = (j == 0);
  const bool pollwave = (tid < 64);
  const int plane = tid & 63;      // poll lane 0..63

  if ((int)blockIdx.x < 64) {
    // ================= stage A: layer-0 GRU =================
    const int wg = blockIdx.x;
    const int eg = wg*8 + g;
    float4 wr[4], wz[4], wn[4];
    {
      const float4* pr_ = (const float4*)(w_hh0 + (size_t)eg*HID + kbase);
      const float4* pz_ = (const float4*)(w_hh0 + (size_t)(512+eg)*HID + kbase);
      const float4* pn_ = (const float4*)(w_hh0 + (size_t)(1024+eg)*HID + kbase);
#pragma unroll
      for (int i = 0; i < 4; i++) { wr[i]=pr_[i]; wz[i]=pz_[i]; wn[i]=pn_[i]; }
    }
    const float bn = b_n0[eg];
    for (int t = 0; t < T_STEPS; t++) {
      float igr=0.f, igz=0.f, ign=0.f;
      if (leader) {  // plain cached loads, issued early (latency hidden)
        const float* ig = ig0 + (size_t)t*G3;
        igr = ig[eg]; igz = ig[512+eg]; ign = ig[1024+eg];
      }
      if (pollwave) {
        // ring-overwrite throttle: steps [t, t+511] overwrite tags <= t+512-R0;
        // require every B WG to have consumed them (cntB >= tag).
        if ((t & 511) == 0 && t >= R0) {
          const unsigned need = (unsigned)(t + 512 - R0);
          while (true) {
            unsigned v = ld_rlx32(&cntB[plane]);
            if (__ballot(v >= need) == ~0ull) break;
            __builtin_amdgcn_s_sleep(8);
          }
        }
        // hint: all A WGs published h0^(t)
        const unsigned need = (unsigned)t;
        while (true) {
          unsigned v = ld_rlx32(&cntA[plane]);
          if (__ballot(v >= need) == ~0ull) break;
          __builtin_amdgcn_s_sleep(1);
        }
      }
      __syncthreads();
      // stage h0^(t) into LDS: thread i verifies elements i, i+256
      {
        const unsigned long long* slot = ring0 + (size_t)(t & (R0-1))*HID;
        const unsigned want = (unsigned)t;
        hbuf0[tid]     = verify_ld(&slot[tid], want);
        hbuf0[tid+256] = verify_ld(&slot[tid+256], want);
      }
      __syncthreads();
      float pr=0.f, pz=0.f, pn=0.f;
      const float4* hp = (const float4*)(hbuf0 + kbase);
#pragma unroll
      for (int i = 0; i < 4; i++) {
        float4 hv = hp[i];
        pr += dot4(wr[i],hv); pz += dot4(wz[i],hv); pn += dot4(wn[i],hv);
      }
#pragma unroll
      for (int s = 16; s > 0; s >>= 1) {
        pr += __shfl_down(pr,s,32);
        pz += __shfl_down(pz,s,32);
        pn += __shfl_down(pn,s,32);
      }
      if (leader) {
        float r = fast_sigmoid(igr + pr);
        float z = fast_sigmoid(igz + pz);
        float n = fast_tanh(ign + r*(pn + bn));
        float hnew = n + z*(hbuf0[eg] - n);
        st_rlx64(&ring0[(size_t)((t+1) & (R0-1))*HID + eg], pack_tv((unsigned)(t+1), hnew));
        if (t == T_STEPS-1) d_out[T_STEPS + eg] = hnew;
      }
      __syncthreads();
      if (tid == 0) st_rlx32(&cntA[wg], (unsigned)(t+1));   // hint only
    }
  } else {
    // ================= stage B: layer-1 GRU =================
    const int wg = (int)blockIdx.x - 64;
    const int eg = wg*8 + g;
    float4 ur[4], uz[4], un[4], vr[4], vz[4], vn[4];
    {
      const float4* a0 = (const float4*)(w_ih1 + (size_t)eg*HID + kbase);
      const float4* a1 = (const float4*)(w_ih1 + (size_t)(512+eg)*HID + kbase);
      const float4* a2 = (const float4*)(w_ih1 + (size_t)(1024+eg)*HID + kbase);
      const float4* b0 = (const float4*)(w_hh1 + (size_t)eg*HID + kbase);
      const float4* b1 = (const float4*)(w_hh1 + (size_t)(512+eg)*HID + kbase);
      const float4* b2 = (const float4*)(w_hh1 + (size_t)(1024+eg)*HID + kbase);
#pragma unroll
      for (int i = 0; i < 4; i++) {
        ur[i]=a0[i]; uz[i]=a1[i]; un[i]=a2[i];
        vr[i]=b0[i]; vz[i]=b1[i]; vn[i]=b2[i];
      }
    }
    const float cr = b_ih1[eg], cz = b_ih1[512+eg], cn = b_ih1[1024+eg];
    const float bnn = b_n1[eg];
    for (int t = 0; t < T_STEPS; t++) {
      if (pollwave) {  // hint: h0^(t+1) and h1^(t) published
        const unsigned needA = (unsigned)(t+1);
        const unsigned needB = (unsigned)t;
        while (true) {
          unsigned va = ld_rlx32(&cntA[plane]);
          unsigned vb = ld_rlx32(&cntB[plane]);
          bool ok = (va >= needA) && (vb >= needB);
          if (__ballot(ok) == ~0ull) break;
          __builtin_amdgcn_s_sleep(1);
        }
      }
      __syncthreads();
      {
        const unsigned long long* s0 = ring0 + (size_t)((t+1) & (R0-1))*HID;
        const unsigned long long* s1 = ring1 + (size_t)(t & (R1-1))*HID;
        const unsigned w0t = (unsigned)(t+1);
        const unsigned w1t = (unsigned)t;
        hbuf0[tid]     = verify_ld(&s0[tid], w0t);
        hbuf0[tid+256] = verify_ld(&s0[tid+256], w0t);
        hbuf1[tid]     = verify_ld(&s1[tid], w1t);
        hbuf1[tid+256] = verify_ld(&s1[tid+256], w1t);
      }
      __syncthreads();
      float pr=0.f, pz=0.f, pin=0.f, phn=0.f;
      const float4* hp0 = (const float4*)(hbuf0 + kbase);
      const float4* hp1 = (const float4*)(hbuf1 + kbase);
#pragma unroll
      for (int i = 0; i < 4; i++) {
        float4 a = hp0[i];
        float4 b = hp1[i];
        pr  += dot4(ur[i],a) + dot4(vr[i],b);
        pz  += dot4(uz[i],a) + dot4(vz[i],b);
        pin += dot4(un[i],a);
        phn += dot4(vn[i],b);
      }
#pragma unroll
      for (int s = 16; s > 0; s >>= 1) {
        pr  += __shfl_down(pr,s,32);
        pz  += __shfl_down(pz,s,32);
        pin += __shfl_down(pin,s,32);
        phn += __shfl_down(phn,s,32);
      }
      if (leader) {
        float r = fast_sigmoid(pr + cr);
        float z = fast_sigmoid(pz + cz);
        float n = fast_tanh(pin + cn + r*(phn + bnn));
        float hnew = n + z*(hbuf1[eg] - n);
        st_rlx64(&ring1[(size_t)((t+1) & (R1-1))*HID + eg], pack_tv((unsigned)(t+1), hnew));
        h1a[(size_t)t*HID + eg] = hnew;   // plain store for the MLP kernel
        if (t == T_STEPS-1) d_out[T_STEPS + HID + eg] = hnew;
      }
      __syncthreads();
      if (tid == 0) st_rlx32(&cntB[wg], (unsigned)(t+1));   // hint only
    }
  }
}

// ---- k4: batched MLP head --------------------------------------------------
__global__ __launch_bounds__(64) void mlp_kernel(
    const float* __restrict__ h1_all, const float* __restrict__ mw0,
    const float* __restrict__ mb0, const float* __restrict__ mw1,
    const float* __restrict__ mb1, const float* __restrict__ mw2,
    const float* __restrict__ mb2, float* __restrict__ out) {
  const int l = threadIdx.x;
  const int t0 = blockIdx.x * 8;
  __shared__ float v0s[8][64];
  float acc[8];
#pragma unroll
  for (int tt = 0; tt < 8; tt++) acc[tt] = mb0[l];
  const float4* w = (const float4*)(mw0 + (size_t)l*512);
#pragma unroll 4
  for (int i = 0; i < 128; i++) {
    float4 a = w[i];
#pragma unroll
    for (int tt = 0; tt < 8; tt++) {
      float4 b = ((const float4*)(h1_all + (size_t)(t0+tt)*512))[i];
      acc[tt] = fmaf(a.x,b.x, fmaf(a.y,b.y, fmaf(a.z,b.z, fmaf(a.w,b.w, acc[tt]))));
    }
  }
#pragma unroll
  for (int tt = 0; tt < 8; tt++) v0s[tt][l] = fmaxf(acc[tt], 0.f);
  __syncthreads();
  float acc1[8];
#pragma unroll
  for (int tt = 0; tt < 8; tt++) acc1[tt] = mb1[l];
  const float* w1 = mw1 + (size_t)l*64;
  for (int jj = 0; jj < 64; jj++) {
    float wv = w1[jj];
#pragma unroll
    for (int tt = 0; tt < 8; tt++) acc1[tt] = fmaf(wv, v0s[tt][jj], acc1[tt]);
  }
  float w2 = mw2[l];
  float bb = mb2[0];
#pragma unroll
  for (int tt = 0; tt < 8; tt++) {
    float y = w2 * fmaxf(acc1[tt], 0.f);
#pragma unroll
    for (int s = 32; s > 0; s >>= 1) y += __shfl_down(y, s, 64);
    if (l == 0) out[t0+tt] = y + bb;
  }
}

// ---------------------------------------------------------------------------
extern "C" void kernel_launch(void* const* d_in, const int* in_sizes, int n_in,
                              void* d_out, int out_size, void* d_ws, size_t ws_size,
                              hipStream_t stream) {
  const float* p0  = (const float*)d_in[0];
  const float* p1  = (const float*)d_in[1];
  const float* p2  = (const float*)d_in[2];
  const float* p3  = (const float*)d_in[3];
  const float* p4  = (const float*)d_in[4];
  const float* p5  = (const float*)d_in[5];
  const float* p6  = (const float*)d_in[6];
  const float* p7  = (const float*)d_in[7];
  const float* p8  = (const float*)d_in[8];
  const float* p9  = (const float*)d_in[9];
  const float* p10 = (const float*)d_in[10];
  const float* p11 = (const float*)d_in[11];
  const float* p12 = (const float*)d_in[12];
  const float* hid   = (const float*)d_in[13];
  const float* w_ih0 = (const float*)d_in[14];
  const float* w_hh0 = (const float*)d_in[15];
  const float* b_ih0 = (const float*)d_in[16];
  const float* b_n0  = (const float*)d_in[17];
  const float* w_ih1 = (const float*)d_in[18];
  const float* w_hh1 = (const float*)d_in[19];
  const float* b_ih1 = (const float*)d_in[20];
  const float* b_n1  = (const float*)d_in[21];
  const float* mw0 = (const float*)d_in[22];
  const float* mb0 = (const float*)d_in[23];
  const float* mw1 = (const float*)d_in[24];
  const float* mb1 = (const float*)d_in[25];
  const float* mw2 = (const float*)d_in[26];
  const float* mb2 = (const float*)d_in[27];
  float* out = (float*)d_out;

  // workspace: ig0 | ring0 | ring1 | cnt | h1a  (obs/wT alias h1a region)
  char* base = (char*)d_ws;
  const size_t IG0_B = (size_t)T_STEPS*G3*4;     // 100,663,296
  const size_t R0_B  = (size_t)R0*HID*8;         //   8,388,608
  const size_t R1_B  = (size_t)R1*HID*8;         //      32,768
  const size_t CNT_B = 1024;
  const size_t H1A_B = (size_t)T_STEPS*HID*4;    //  33,554,432
  float* ig0 = (float*)base;
  unsigned long long* ring0 = (unsigned long long*)(base + IG0_B);
  unsigned long long* ring1 = (unsigned long long*)(base + IG0_B + R0_B);
  unsigned* cntA = (unsigned*)(base + IG0_B + R0_B + R1_B);
  unsigned* cntB = cntA + 64;
  float* h1a = (float*)(base + IG0_B + R0_B + R1_B + CNT_B);
  float* obs = h1a;                                           // alias
  float* wT  = (float*)((char*)h1a + (size_t)T_STEPS*IN_DIM*4);  // alias
  if (ws_size < IG0_B + R0_B + R1_B + CNT_B + H1A_B) return;  // 142,640,128 B

  hipMemsetAsync(cntA, 0, CNT_B, stream);
  concat_kernel<<<T_STEPS, 384, 0, stream>>>(p0,p1,p2,p3,p4,p5,p6,p7,p8,p9,p10,p11,p12, obs);
  transpose_kernel<<<dim3(11,48), dim3(32,8), 0, stream>>>(w_ih0, wT);
  ig0_kernel<<<dim3(6, T_STEPS/TTILE), 256, 0, stream>>>(wT, obs, b_ih0, ig0);
  init_kernel<<<1, 512, 0, stream>>>(hid, ring0, ring1);
  seq_kernel<<<128, 256, 0, stream>>>(ig0, w_hh0, b_n0, w_ih1, w_hh1, b_ih1, b_n1,
                                      hid, ring0, ring1, cntA, cntB, h1a, out);
  mlp_kernel<<<T_STEPS/8, 64, 0, stream>>>(h1a, mw0, mb0, mw1, mb1, mw2, mb2, out);
}

// Round 5
// 31845.850 us; speedup vs baseline: 10.4083x; 2.1413x over previous
//
#include <hip/hip_runtime.h>
#include <math.h>

// ---------------------------------------------------------------------------
// DefaultHumanoidGRUCritic on MI355X — round 5
//
// Round-4 measured: 6.04e8 LDS bank conflicts (16-way: float4 reads at
// 16-float lane stride) and a redundant hint-poll hop (cntA published a full
// barrier after the data; B serialized on it). Round-5 changes:
//   * conflict-free LDS mapping: 16-lane group reads float4 chunks jj+16*i
//     (64 words/instr across 16 lanes, <=2-way = free); weights gathered to
//     match (global loads stay coalesced).
//   * NO hint polls: tagged verify loads with s_sleep backoff are the only
//     wait (round-4-proven primitive). Only A's ring-overwrite throttle
//     remains (every 512 steps, polls cntB).
//   * fewer/fatter WGs: A=16 WGs x 512 thr (32 el/WG), B=32 WGs x 512 thr
//     (16 el/WG; 32-lane group = ih-half + hh-half, 16 lanes each).
//     Staging traffic 768 -> ~320 KB/step; 1 verify word/thread/buffer.
//
//   k0 concat, k1 transpose, k2 ig0 (parallel over T; obs/wT alias h1a)
//   k_init: seed ring0/ring1 slot 0 (tag 0) with initial hidden state
//   k3 seq: 48 WGs x 512 (16 stage-A, 32 stage-B), fence-free tagged rings
//   k4 mlp: batched projector head over h1a -> d_out[0..T)
// Final hidden -> d_out[T .. T+1024).
// ---------------------------------------------------------------------------

#define T_STEPS 16384
#define IN_DIM 341
#define HID 512
#define G3 1536
#define TTILE 16
#define R0 2048
#define R0M (R0-1)
#define R1 8
#define R1M (R1-1)

__device__ __forceinline__ float dot4(float4 a, float4 b) {
  return fmaf(a.x, b.x, fmaf(a.y, b.y, fmaf(a.z, b.z, a.w * b.w)));
}
__device__ __forceinline__ float fast_sigmoid(float x) {
  return __builtin_amdgcn_rcpf(1.0f + __expf(-x));
}
__device__ __forceinline__ float fast_tanh(float x) {
  return fmaf(-2.0f, __builtin_amdgcn_rcpf(1.0f + __expf(2.0f * x)), 1.0f);
}
__device__ __forceinline__ unsigned long long ld_rlx64(const unsigned long long* p) {
  return __hip_atomic_load(p, __ATOMIC_RELAXED, __HIP_MEMORY_SCOPE_AGENT);
}
__device__ __forceinline__ void st_rlx64(unsigned long long* p, unsigned long long v) {
  __hip_atomic_store(p, v, __ATOMIC_RELAXED, __HIP_MEMORY_SCOPE_AGENT);
}
__device__ __forceinline__ unsigned ld_rlx32(const unsigned* p) {
  return __hip_atomic_load(p, __ATOMIC_RELAXED, __HIP_MEMORY_SCOPE_AGENT);
}
__device__ __forceinline__ void st_rlx32(unsigned* p, unsigned v) {
  __hip_atomic_store(p, v, __ATOMIC_RELAXED, __HIP_MEMORY_SCOPE_AGENT);
}
__device__ __forceinline__ unsigned long long pack_tv(unsigned tag, float v) {
  return ((unsigned long long)tag << 32) | (unsigned long long)__float_as_uint(v);
}
// tagged verify load with backoff: fast path = single load when data present
__device__ __forceinline__ float verify_ld(const unsigned long long* p, unsigned want) {
  unsigned long long w = ld_rlx64(p);
  while ((unsigned)(w >> 32) != want) {
    __builtin_amdgcn_s_sleep(1);
    w = ld_rlx64(p);
  }
  return __uint_as_float((unsigned)w);
}

// ---- k0: concat observations ----------------------------------------------
__global__ __launch_bounds__(384) void concat_kernel(
    const float* __restrict__ p0, const float* __restrict__ p1,
    const float* __restrict__ p2, const float* __restrict__ p3,
    const float* __restrict__ p4, const float* __restrict__ p5,
    const float* __restrict__ p6, const float* __restrict__ p7,
    const float* __restrict__ p8, const float* __restrict__ p9,
    const float* __restrict__ p10, const float* __restrict__ p11,
    const float* __restrict__ p12, float* __restrict__ obs) {
  int t = blockIdx.x;
  int k = threadIdx.x;
  if (k >= IN_DIM) return;
  float v;
  if (k < 21)       v = p0[t*21 + k];
  else if (k < 42)  v = p1[t*21 + (k-21)];
  else if (k < 202) v = p2[t*160 + (k-42)];
  else if (k < 298) v = p3[t*96 + (k-202)];
  else if (k < 301) v = p4[t*3 + (k-298)];
  else if (k < 304) v = p5[t*3 + (k-301)];
  else if (k < 325) v = p6[t*21 + (k-304)];
  else if (k < 328) v = p7[t*3 + (k-325)];
  else if (k < 332) v = p8[t*4 + (k-328)];
  else if (k < 335) v = p9[t*3 + (k-332)];
  else if (k < 338) v = p10[t*3 + (k-335)];
  else if (k < 340) v = p11[t*2 + (k-338)];
  else              v = p12[t];
  obs[(size_t)t*IN_DIM + k] = v;
}

// ---- k1: transpose w_ih0 ---------------------------------------------------
__global__ __launch_bounds__(256) void transpose_kernel(const float* __restrict__ w,
                                                        float* __restrict__ wT) {
  __shared__ float tile[32][33];
  int tx = threadIdx.x;  // 32
  int ty = threadIdx.y;  // 8
  int k = blockIdx.x*32 + tx;
#pragma unroll
  for (int jj = 0; jj < 4; jj++) {
    int r = blockIdx.y*32 + ty*4 + jj;
    tile[ty*4+jj][tx] = (k < IN_DIM) ? w[(size_t)r*IN_DIM + k] : 0.f;
  }
  __syncthreads();
#pragma unroll
  for (int jj = 0; jj < 4; jj++) {
    int kk = blockIdx.x*32 + ty*4 + jj;
    if (kk < IN_DIM) wT[(size_t)kk*G3 + blockIdx.y*32 + tx] = tile[tx][ty*4+jj];
  }
}

// ---- k2: IG0 = obs @ w_ih0^T + b_ih0 --------------------------------------
__global__ __launch_bounds__(256) void ig0_kernel(const float* __restrict__ wT,
                                                  const float* __restrict__ obs,
                                                  const float* __restrict__ b_ih0,
                                                  float* __restrict__ ig0) {
  int o = blockIdx.x*256 + threadIdx.x;
  int t0 = blockIdx.y * TTILE;
  float acc[TTILE];
  float b = b_ih0[o];
#pragma unroll
  for (int tt = 0; tt < TTILE; tt++) acc[tt] = b;
  for (int k = 0; k < IN_DIM; k++) {
    float wv = wT[(size_t)k*G3 + o];
#pragma unroll
    for (int tt = 0; tt < TTILE; tt++)
      acc[tt] = fmaf(obs[(size_t)(t0+tt)*IN_DIM + k], wv, acc[tt]);
  }
#pragma unroll
  for (int tt = 0; tt < TTILE; tt++)
    ig0[(size_t)(t0+tt)*G3 + o] = acc[tt];
}

// ---- k_init: seed ring slot 0 with tagged initial hidden -------------------
__global__ __launch_bounds__(512) void init_kernel(const float* __restrict__ hid,
                                                   unsigned long long* ring0,
                                                   unsigned long long* ring1) {
  int e = threadIdx.x;
  st_rlx64(&ring0[e], pack_tv(0u, hid[e]));
  st_rlx64(&ring1[e], pack_tv(0u, hid[HID + e]));
}

// ---- k3: sequential GRU scan ----------------------------------------------
// 48 WGs x 512 threads. WGs [0,16): stage A (layer 0), 32 elements each,
// one 16-lane group per element, K-slice 32/lane as float4 chunks jj+16*i
// (conflict-free LDS). WGs [16,48): stage B (layer 1), 16 elements each,
// one 32-lane group per element split into ih-half (lanes 0-15, reads h0)
// and hh-half (lanes 16-31, reads h1).
__global__ __launch_bounds__(512, 2) void seq_kernel(
    const float* __restrict__ ig0, const float* __restrict__ w_hh0,
    const float* __restrict__ b_n0, const float* __restrict__ w_ih1,
    const float* __restrict__ w_hh1, const float* __restrict__ b_ih1,
    const float* __restrict__ b_n1,
    unsigned long long* ring0, unsigned long long* ring1, unsigned* cntB,
    float* __restrict__ h1a, float* __restrict__ d_out) {
  __shared__ float hbuf0[HID];
  __shared__ float hbuf1[HID];
  __shared__ float igbuf[96];
  const int tid = threadIdx.x;

  if ((int)blockIdx.x < 16) {
    // ================= stage A: layer-0 GRU =================
    const int wg = blockIdx.x;
    const int g  = tid >> 4;        // 0..31: element group
    const int jj = tid & 15;        // lane within group
    const int eg = wg*32 + g;       // global h0 element
    const bool leader = (jj == 0);
    // weights as float4 chunks jj+16*i  (k-values 4jj+64i+c)
    float4 wr[8], wz[8], wn[8];
    {
      const float4* pr_ = (const float4*)(w_hh0 + (size_t)eg*HID);
      const float4* pz_ = (const float4*)(w_hh0 + (size_t)(512+eg)*HID);
      const float4* pn_ = (const float4*)(w_hh0 + (size_t)(1024+eg)*HID);
#pragma unroll
      for (int i = 0; i < 8; i++) {
        wr[i] = pr_[jj + 16*i]; wz[i] = pz_[jj + 16*i]; wn[i] = pn_[jj + 16*i];
      }
    }
    const float bn = b_n0[eg];
    for (int t = 0; t < T_STEPS; t++) {
      // ring-overwrite throttle: steps [t,t+511] overwrite tags <= t+512-R0;
      // every B WG must have consumed them (cntB >= tag). Wave 0 polls; the
      // post-staging __syncthreads gates the publish.
      if ((t & 511) == 0 && t >= R0 && tid < 64) {
        const unsigned need = (unsigned)(t + 512 - R0);
        while (true) {
          unsigned v = ld_rlx32(&cntB[tid & 31]);
          if (__ballot(v >= need) == ~0ull) break;
          __builtin_amdgcn_s_sleep(16);
        }
      }
      // prefetch this WG's ig0 slice (96 values) into LDS
      if (tid < 96) {
        int gate = tid >> 5, e = tid & 31;
        igbuf[tid] = ig0[(size_t)t*G3 + gate*HID + wg*32 + e];
      }
      // stage h0^(t): thread i verifies element i
      hbuf0[tid] = verify_ld(&ring0[(size_t)(t & R0M)*HID + tid], (unsigned)t);
      __syncthreads();
      float pr=0.f, pz=0.f, pn=0.f;
      const float4* hp = (const float4*)hbuf0;
#pragma unroll
      for (int i = 0; i < 8; i++) {
        float4 hv = hp[jj + 16*i];   // words 4jj+64i: conflict-free
        pr += dot4(wr[i],hv); pz += dot4(wz[i],hv); pn += dot4(wn[i],hv);
      }
#pragma unroll
      for (int s = 1; s < 16; s <<= 1) {
        pr += __shfl_xor(pr, s, 16);
        pz += __shfl_xor(pz, s, 16);
        pn += __shfl_xor(pn, s, 16);
      }
      if (leader) {
        float r = fast_sigmoid(igbuf[g] + pr);
        float z = fast_sigmoid(igbuf[32+g] + pz);
        float n = fast_tanh(igbuf[64+g] + r*(pn + bn));
        float hnew = n + z*(hbuf0[eg] - n);
        st_rlx64(&ring0[(size_t)((t+1) & R0M)*HID + eg],
                 pack_tv((unsigned)(t+1), hnew));
        if (t == T_STEPS-1) d_out[T_STEPS + eg] = hnew;
      }
      __syncthreads();   // protect hbuf0/igbuf before next iteration
    }
  } else {
    // ================= stage B: layer-1 GRU =================
    const int wg  = (int)blockIdx.x - 16;  // 0..31
    const int g   = tid >> 5;              // 0..15: element group
    const int j32 = tid & 31;
    const int half = j32 >> 4;             // 0 = ih (reads h0), 1 = hh (reads h1)
    const int jj  = j32 & 15;
    const int eg  = wg*16 + g;             // global h1 element
    const bool leader = (j32 == 0);
    const float* Wm = half ? w_hh1 : w_ih1;
    float4 ar[8], az[8], an[8];
    {
      const float4* pr_ = (const float4*)(Wm + (size_t)eg*HID);
      const float4* pz_ = (const float4*)(Wm + (size_t)(512+eg)*HID);
      const float4* pn_ = (const float4*)(Wm + (size_t)(1024+eg)*HID);
#pragma unroll
      for (int i = 0; i < 8; i++) {
        ar[i] = pr_[jj + 16*i]; az[i] = pz_[jj + 16*i]; an[i] = pn_[jj + 16*i];
      }
    }
    const float cr = b_ih1[eg], cz = b_ih1[512+eg], cn = b_ih1[1024+eg];
    const float bnn = b_n1[eg];
    for (int t = 0; t < T_STEPS; t++) {
      // stage h0^(t) [published as tag t+1] and h1^(t-1) [tag t]
      hbuf0[tid] = verify_ld(&ring0[(size_t)((t+1) & R0M)*HID + tid], (unsigned)(t+1));
      hbuf1[tid] = verify_ld(&ring1[(size_t)(t & R1M)*HID + tid], (unsigned)t);
      __syncthreads();
      const float4* hp = (const float4*)(half ? hbuf1 : hbuf0);
      float pr=0.f, pz=0.f, pn=0.f;
#pragma unroll
      for (int i = 0; i < 8; i++) {
        float4 hv = hp[jj + 16*i];
        pr += dot4(ar[i],hv); pz += dot4(az[i],hv); pn += dot4(an[i],hv);
      }
#pragma unroll
      for (int s = 1; s < 16; s <<= 1) {   // width 16: halves reduce separately
        pr += __shfl_xor(pr, s, 16);
        pz += __shfl_xor(pz, s, 16);
        pn += __shfl_xor(pn, s, 16);
      }
      // harvest hh-half sums (lane 16 of the 32-lane group)
      float qr = __shfl(pr, 16, 32);
      float qz = __shfl(pz, 16, 32);
      float qn = __shfl(pn, 16, 32);
      if (leader) {
        float r = fast_sigmoid(pr + cr + qr);
        float z = fast_sigmoid(pz + cz + qz);
        float n = fast_tanh(pn + cn + r*(qn + bnn));
        float hnew = n + z*(hbuf1[eg] - n);
        st_rlx64(&ring1[(size_t)((t+1) & R1M)*HID + eg],
                 pack_tv((unsigned)(t+1), hnew));
        h1a[(size_t)t*HID + eg] = hnew;   // plain store for the MLP kernel
        if (t == T_STEPS-1) d_out[T_STEPS + HID + eg] = hnew;
      }
      __syncthreads();
      if (tid == 0 && (t & 31) == 31)
        st_rlx32(&cntB[wg], (unsigned)(t+1));   // throttle progress (coarse)
    }
  }
}

// ---- k4: batched MLP head --------------------------------------------------
__global__ __launch_bounds__(64) void mlp_kernel(
    const float* __restrict__ h1_all, const float* __restrict__ mw0,
    const float* __restrict__ mb0, const float* __restrict__ mw1,
    const float* __restrict__ mb1, const float* __restrict__ mw2,
    const float* __restrict__ mb2, float* __restrict__ out) {
  const int l = threadIdx.x;
  const int t0 = blockIdx.x * 8;
  __shared__ float v0s[8][64];
  float acc[8];
#pragma unroll
  for (int tt = 0; tt < 8; tt++) acc[tt] = mb0[l];
  const float4* w = (const float4*)(mw0 + (size_t)l*512);
#pragma unroll 4
  for (int i = 0; i < 128; i++) {
    float4 a = w[i];
#pragma unroll
    for (int tt = 0; tt < 8; tt++) {
      float4 b = ((const float4*)(h1_all + (size_t)(t0+tt)*512))[i];
      acc[tt] = fmaf(a.x,b.x, fmaf(a.y,b.y, fmaf(a.z,b.z, fmaf(a.w,b.w, acc[tt]))));
    }
  }
#pragma unroll
  for (int tt = 0; tt < 8; tt++) v0s[tt][l] = fmaxf(acc[tt], 0.f);
  __syncthreads();
  float acc1[8];
#pragma unroll
  for (int tt = 0; tt < 8; tt++) acc1[tt] = mb1[l];
  const float* w1 = mw1 + (size_t)l*64;
  for (int jj = 0; jj < 64; jj++) {
    float wv = w1[jj];
#pragma unroll
    for (int tt = 0; tt < 8; tt++) acc1[tt] = fmaf(wv, v0s[tt][jj], acc1[tt]);
  }
  float w2 = mw2[l];
  float bb = mb2[0];
#pragma unroll
  for (int tt = 0; tt < 8; tt++) {
    float y = w2 * fmaxf(acc1[tt], 0.f);
#pragma unroll
    for (int s = 32; s > 0; s >>= 1) y += __shfl_down(y, s, 64);
    if (l == 0) out[t0+tt] = y + bb;
  }
}

// ---------------------------------------------------------------------------
extern "C" void kernel_launch(void* const* d_in, const int* in_sizes, int n_in,
                              void* d_out, int out_size, void* d_ws, size_t ws_size,
                              hipStream_t stream) {
  const float* p0  = (const float*)d_in[0];
  const float* p1  = (const float*)d_in[1];
  const float* p2  = (const float*)d_in[2];
  const float* p3  = (const float*)d_in[3];
  const float* p4  = (const float*)d_in[4];
  const float* p5  = (const float*)d_in[5];
  const float* p6  = (const float*)d_in[6];
  const float* p7  = (const float*)d_in[7];
  const float* p8  = (const float*)d_in[8];
  const float* p9  = (const float*)d_in[9];
  const float* p10 = (const float*)d_in[10];
  const float* p11 = (const float*)d_in[11];
  const float* p12 = (const float*)d_in[12];
  const float* hid   = (const float*)d_in[13];
  const float* w_ih0 = (const float*)d_in[14];
  const float* w_hh0 = (const float*)d_in[15];
  const float* b_ih0 = (const float*)d_in[16];
  const float* b_n0  = (const float*)d_in[17];
  const float* w_ih1 = (const float*)d_in[18];
  const float* w_hh1 = (const float*)d_in[19];
  const float* b_ih1 = (const float*)d_in[20];
  const float* b_n1  = (const float*)d_in[21];
  const float* mw0 = (const float*)d_in[22];
  const float* mb0 = (const float*)d_in[23];
  const float* mw1 = (const float*)d_in[24];
  const float* mb1 = (const float*)d_in[25];
  const float* mw2 = (const float*)d_in[26];
  const float* mb2 = (const float*)d_in[27];
  float* out = (float*)d_out;

  // workspace: ig0 | ring0 | ring1 | cntB | h1a  (obs/wT alias h1a region)
  char* base = (char*)d_ws;
  const size_t IG0_B = (size_t)T_STEPS*G3*4;     // 100,663,296
  const size_t R0_B  = (size_t)R0*HID*8;         //   8,388,608
  const size_t R1_B  = (size_t)R1*HID*8;         //      32,768
  const size_t CNT_B = 1024;
  const size_t H1A_B = (size_t)T_STEPS*HID*4;    //  33,554,432
  float* ig0 = (float*)base;
  unsigned long long* ring0 = (unsigned long long*)(base + IG0_B);
  unsigned long long* ring1 = (unsigned long long*)(base + IG0_B + R0_B);
  unsigned* cntB = (unsigned*)(base + IG0_B + R0_B + R1_B);
  float* h1a = (float*)(base + IG0_B + R0_B + R1_B + CNT_B);
  float* obs = h1a;                                              // alias
  float* wT  = (float*)((char*)h1a + (size_t)T_STEPS*IN_DIM*4);  // alias
  if (ws_size < IG0_B + R0_B + R1_B + CNT_B + H1A_B) return;

  hipMemsetAsync(cntB, 0, CNT_B, stream);
  concat_kernel<<<T_STEPS, 384, 0, stream>>>(p0,p1,p2,p3,p4,p5,p6,p7,p8,p9,p10,p11,p12, obs);
  transpose_kernel<<<dim3(11,48), dim3(32,8), 0, stream>>>(w_ih0, wT);
  ig0_kernel<<<dim3(6, T_STEPS/TTILE), 256, 0, stream>>>(wT, obs, b_ih0, ig0);
  init_kernel<<<1, 512, 0, stream>>>(hid, ring0, ring1);
  seq_kernel<<<48, 512, 0, stream>>>(ig0, w_hh0, b_n0, w_ih1, w_hh1, b_ih1, b_n1,
                                     ring0, ring1, cntB, h1a, out);
  mlp_kernel<<<T_STEPS/8, 64, 0, stream>>>(h1a, mw0, mb0, mw1, mb1, mw2, mb2, out);
}